// Round 8
// baseline (368.100 us; speedup 1.0000x reference)
//
#include <hip/hip_runtime.h>

// BPS tokenizer: per (batch, basis) argmin_n |pc[b,n]-basis[p]|^2 -> [dist,dx,dy,dz].
// B=16, N=4096, P=4096.
//
// R8: exact sphere-pruned chunk search (dense all-pairs VALU floor ~20us reached;
// cut the interaction count ~25x instead).
//  Kernel bps_bin (17 blocks x 1024):
//   blocks 0-15: per-batch Morton counting-sort of points (16^3 cells on [-4,4]^3,
//     hist+scan+scatter in LDS) -> spts[b][4096] float4(x,y,z,|p|^2), sidx (orig n,
//     u16); 128 chunks of 32 sorted pts each get a CONSERVATIVE bounding sphere
//     (centroid, r = max-dist*1.0005+1e-6) -> chunkA = (-2cx,-2cy,-2cz,|c|^2), chunkR.
//   block 16: Morton-sort the basis (16^3 on [-1,1]^3) -> perm (wave-coherent queries).
//  Kernel bps_query (1024 blocks x 64): lane = one sorted-rank basis point.
//   pass1: nearest-centroid chunk kbest (128 sphere recs, wave-uniform -> scalar loads);
//   scan kbest exactly: key = fmaf(x,-2bx,fmaf(y,-2by,fmaf(z,-2bz,w))) = d2-|b|^2 --
//   IDENTICAL chain to R6/R7 (passed, absmax 4.88e-4); lex (key, orig n) tie-break
//   (sidx fetched only on exact key tie).
//   pass2: prune chunk k unless d2c < (r_k + sb)^2 + 1e-4, sb^2 = max(key+bsq,0)+1e-4.
//   Margins (1e-4) >> f32 chain error (~2e-5) -> scanned set provably contains all
//   candidates within rounding of the min -> same winner as dense rounds.
//   Chunk membership varies with atomic scatter order, but spheres are computed from
//   actual members and pruning is conservative -> output deterministic.

#define NCHK 128
#define CHKSZ 32
#define MARG 1e-4f

__device__ __forceinline__ unsigned int mpart(unsigned int v) {
    return (v & 1u) | ((v & 2u) << 2) | ((v & 4u) << 4) | ((v & 8u) << 6);
}
__device__ __forceinline__ int clamp16(int c) { return c < 0 ? 0 : (c > 15 ? 15 : c); }
__device__ __forceinline__ unsigned int morton16(float x, float y, float z, float off, float sc) {
    int cx = clamp16((int)floorf((x + off) * sc));
    int cy = clamp16((int)floorf((y + off) * sc));
    int cz = clamp16((int)floorf((z + off) * sc));
    return mpart((unsigned)cx) | (mpart((unsigned)cy) << 1) | (mpart((unsigned)cz) << 2);
}

// ---------------- bin/sort kernel: blocks 0-15 = batches, block 16 = basis ----------------
__global__ __launch_bounds__(1024) void bps_bin(
    const float* __restrict__ pc, const float* __restrict__ basis,
    float4* __restrict__ spts, float4* __restrict__ chunkA,
    float* __restrict__ chunkR, int* __restrict__ perm,
    unsigned short* __restrict__ sidx)
{
#pragma clang fp contract(off)
    __shared__ unsigned int hist[4096];
    __shared__ unsigned int sA[1024], sB[1024];
    __shared__ float4 cloudL[4096];

    const int t = threadIdx.x;
    const int blk = blockIdx.x;
    const bool isB = (blk == 16);
    const int b = isB ? 0 : blk;

    #pragma unroll
    for (int i = 0; i < 4; ++i) hist[4 * t + i] = 0u;

    float X[4], Y[4], Z[4];
    unsigned int mc[4];
    if (!isB) {
        const float4* pc4 = (const float4*)(pc + (size_t)b * 12288);
        const float4 f0 = pc4[3 * t], f1 = pc4[3 * t + 1], f2 = pc4[3 * t + 2];
        X[0] = f0.x; X[1] = f0.w; X[2] = f1.z; X[3] = f2.y;
        Y[0] = f0.y; Y[1] = f1.x; Y[2] = f1.w; Y[3] = f2.z;
        Z[0] = f0.z; Z[1] = f1.y; Z[2] = f2.x; Z[3] = f2.w;
        #pragma unroll
        for (int j = 0; j < 4; ++j) mc[j] = morton16(X[j], Y[j], Z[j], 4.0f, 2.0f);
    } else {
        #pragma unroll
        for (int j = 0; j < 4; ++j) {
            const int p = 4 * t + j;
            X[j] = basis[3 * p]; Y[j] = basis[3 * p + 1]; Z[j] = basis[3 * p + 2];
            mc[j] = morton16(X[j], Y[j], Z[j], 1.0f, 8.0f);
        }
    }
    __syncthreads();                       // hist zeroed
    #pragma unroll
    for (int j = 0; j < 4; ++j) atomicAdd(&hist[mc[j]], 1u);
    __syncthreads();

    // exclusive scan of hist[4096]: per-thread sum of 4 + 10-step ping-pong scan
    const unsigned int h0 = hist[4 * t], h1 = hist[4 * t + 1],
                       h2 = hist[4 * t + 2], h3 = hist[4 * t + 3];
    sA[t] = h0 + h1 + h2 + h3;
    __syncthreads();
    unsigned int off = 1;
    #pragma unroll
    for (int s = 0; s < 10; ++s) {
        if (s & 1) sA[t] = sB[t] + ((t >= (int)off) ? sB[t - off] : 0u);
        else       sB[t] = sA[t] + ((t >= (int)off) ? sA[t - off] : 0u);
        off <<= 1;
        __syncthreads();
    }
    const unsigned int excl = (t == 0) ? 0u : sA[t - 1];  // inclusive ends in sA (10 steps)
    hist[4 * t]     = excl;
    hist[4 * t + 1] = excl + h0;
    hist[4 * t + 2] = excl + h0 + h1;
    hist[4 * t + 3] = excl + h0 + h1 + h2;
    __syncthreads();

    if (!isB) {
        #pragma unroll
        for (int j = 0; j < 4; ++j) {
            const unsigned int slot = atomicAdd(&hist[mc[j]], 1u);
            const float w = (X[j] * X[j] + Y[j] * Y[j]) + Z[j] * Z[j];  // ref op order
            const float4 v = make_float4(X[j], Y[j], Z[j], w);
            cloudL[slot] = v;
            spts[((size_t)b << 12) + slot] = v;
            sidx[((size_t)b << 12) + slot] = (unsigned short)(4 * t + j);
        }
        __syncthreads();
        if (t < NCHK) {   // conservative bounding sphere per 32-pt chunk
            float sx = 0.f, sy = 0.f, sz = 0.f;
            #pragma unroll
            for (int j = 0; j < CHKSZ; ++j) {
                const float4 v = cloudL[CHKSZ * t + j];
                sx += v.x; sy += v.y; sz += v.z;
            }
            const float cx = sx * 0.03125f, cy = sy * 0.03125f, cz = sz * 0.03125f;
            float m2 = 0.f;
            #pragma unroll
            for (int j = 0; j < CHKSZ; ++j) {
                const float4 v = cloudL[CHKSZ * t + j];
                const float dx = v.x - cx, dy = v.y - cy, dz = v.z - cz;
                m2 = fmaxf(m2, (dx * dx + dy * dy) + dz * dz);
            }
            const float r = sqrtf(m2) * 1.0005f + 1e-6f;
            chunkA[(b << 7) + t] = make_float4(-2.f * cx, -2.f * cy, -2.f * cz,
                                               (cx * cx + cy * cy) + cz * cz);
            chunkR[(b << 7) + t] = r;
        }
    } else {
        #pragma unroll
        for (int j = 0; j < 4; ++j) {
            const unsigned int slot = atomicAdd(&hist[mc[j]], 1u);
            perm[slot] = 4 * t + j;
        }
    }
}

// ---------------- query kernel: one lane per (batch, sorted basis rank) ----------------
__global__ __launch_bounds__(64) void bps_query(
    const float* __restrict__ basis,
    const float4* __restrict__ spts,
    const float4* __restrict__ chunkA,
    const float* __restrict__ chunkR,
    const int* __restrict__ perm,
    const unsigned short* __restrict__ sidx,
    float* __restrict__ out)
{
#pragma clang fp contract(off)
    const int bid  = blockIdx.x;
    const int b    = bid >> 6;
    const int rank = ((bid & 63) << 6) + threadIdx.x;
    const int p    = perm[rank];

    const float bx = basis[3 * p], by = basis[3 * p + 1], bz = basis[3 * p + 2];
    const float bxm2 = -2.f * bx, bym2 = -2.f * by, bzm2 = -2.f * bz;
    const float bsq = (bx * bx + by * by) + bz * bz;

    const float4* cA = chunkA + (b << 7);          // wave-uniform k -> scalar loads
    const float*  cR = chunkR + (b << 7);
    const float4* cl = spts + ((size_t)b << 12);
    const unsigned short* si = sidx + ((size_t)b << 12);

    // pass 1: nearest centroid
    float bestc = __builtin_inff();
    int kbest = 0;
    for (int k = 0; k < NCHK; ++k) {
        const float4 A = cA[k];
        const float d2c = fmaf(A.x, bx, fmaf(A.y, by, fmaf(A.z, bz, A.w))) + bsq;
        if (d2c < bestc) { bestc = d2c; kbest = k; }
    }

    float bkey = __builtin_inff();
    int bslot = 0;
    auto scan_chunk = [&](int k) {
        const float4* cp = cl + (k << 5);
        #pragma unroll
        for (int j = 0; j < CHKSZ; ++j) {
            const float4 v = cp[j];
            // IDENTICAL key chain to R6/R7 dense rounds
            const float key = fmaf(v.x, bxm2, fmaf(v.y, bym2, fmaf(v.z, bzm2, v.w)));
            const int slot = (k << 5) + j;
            if (key < bkey) { bkey = key; bslot = slot; }
            else if (key == bkey) {                      // rare exact tie: first orig index
                const int n_new = si[slot];
                const int n_old = si[bslot];
                if (n_new < n_old) bslot = slot;
            }
        }
    };

    scan_chunk(kbest);
    float sb = sqrtf(fmaxf(bkey + bsq, 0.f) + MARG);

    // pass 2: conservative sphere pruning
    for (int k = 0; k < NCHK; ++k) {
        if (k == kbest) continue;
        const float4 A = cA[k];
        const float d2c = fmaf(A.x, bx, fmaf(A.y, by, fmaf(A.z, bz, A.w))) + bsq;
        const float tr = cR[k] + sb;
        if (d2c < fmaf(tr, tr, MARG)) {
            scan_chunk(k);
            sb = sqrtf(fmaxf(bkey + bsq, 0.f) + MARG);
        }
    }

    const float4 v = cl[bslot];
    const float dx = v.x - bx, dy = v.y - by, dz = v.z - bz;
    const float dist = sqrtf((dx * dx + dy * dy) + dz * dz);   // ref op order
    ((float4*)out)[((size_t)b << 12) + p] = make_float4(dist, dx, dy, dz);
}

extern "C" void kernel_launch(void* const* d_in, const int* in_sizes, int n_in,
                              void* d_out, int out_size, void* d_ws, size_t ws_size,
                              hipStream_t stream) {
    const float* pc    = (const float*)d_in[0];  // [16, 4096, 3]
    const float* basis = (const float*)d_in[1];  // [4096, 3]
    float* out = (float*)d_out;                  // [16, 4096, 4]

    char* ws = (char*)d_ws;
    float4*         spts   = (float4*)(ws);                      // 1 MB
    float4*         chunkA = (float4*)(ws + 1048576);            // 32 KB
    float*          chunkR = (float*) (ws + 1048576 + 32768);    // 8 KB
    int*            perm   = (int*)   (ws + 1048576 + 40960);    // 16 KB
    unsigned short* sidx   = (unsigned short*)(ws + 1048576 + 57344); // 128 KB

    bps_bin<<<dim3(17), dim3(1024), 0, stream>>>(pc, basis, spts, chunkA, chunkR, perm, sidx);
    bps_query<<<dim3(1024), dim3(64), 0, stream>>>(basis, spts, chunkA, chunkR, perm, sidx, out);
}

// Round 9
// 81.226 us; speedup vs baseline: 4.5318x; 4.5318x over previous
//
#include <hip/hip_runtime.h>

// BPS tokenizer: per (batch, basis) argmin_n |pc[b,n]-basis[p]|^2 -> [dist,dx,dy,dz].
// B=16, N=4096, P=4096.
//
// R9 = R8's exact sphere-pruned search, restructured for occupancy:
//  bps_bin (17 blocks x 1024): per-batch Morton counting-sort (16^3 cells on
//   [-4,4]^3) -> spts (sorted float4 x,y,z,|p|^2), sidx (orig n), 128 chunk
//   spheres (conservative), 16 super-spheres (r = max_j |c_j-C|+r_j, conservative
//   by triangle ineq), cellstart[4096] (first sorted slot with cell >= c);
//   block 16 Morton-sorts the basis -> perm.
//  bps_query (512 blocks x 512): block = (batch, 128 sorted-rank queries).
//   Stages cloud+spheres+cellstart in LDS (~77 KB, 2 blocks/CU, 16 waves/CU).
//   QUAD per query (4 lanes): seed chunk from cellstart -> scan -> sb;
//   16 super tests (4/lane) -> passing supers' 8 subs tested (2/lane) ->
//   hit chunks scanned cooperatively (8 pts/lane), sb tightened per chunk.
//   Keys use the IDENTICAL fmaf chain as R6/R7/R8 (passed, absmax 4.88e-4);
//   exact key ties resolved by original index (global sidx, rare).
//   Margins 1e-4 >> fp chain error -> pruned points provably can't win or tie.
//   Chunk LDS stride = 33 float4 (528B) so quad bases spread banks (~2-way, free).

#define NCHK 128
#define CHKSZ 32
#define CSTRIDE 33
#define MARG 1e-4f

__device__ __forceinline__ unsigned int mpart(unsigned int v) {
    return (v & 1u) | ((v & 2u) << 2) | ((v & 4u) << 4) | ((v & 8u) << 6);
}
__device__ __forceinline__ int clamp16(int c) { return c < 0 ? 0 : (c > 15 ? 15 : c); }
__device__ __forceinline__ unsigned int morton16(float x, float y, float z, float off, float sc) {
    int cx = clamp16((int)floorf((x + off) * sc));
    int cy = clamp16((int)floorf((y + off) * sc));
    int cz = clamp16((int)floorf((z + off) * sc));
    return mpart((unsigned)cx) | (mpart((unsigned)cy) << 1) | (mpart((unsigned)cz) << 2);
}

// ---------------- bin/sort kernel: blocks 0-15 = batches, block 16 = basis ----------------
__global__ __launch_bounds__(1024) void bps_bin(
    const float* __restrict__ pc, const float* __restrict__ basis,
    float4* __restrict__ spts, float4* __restrict__ chunkA, float* __restrict__ chunkR,
    float4* __restrict__ superA, float* __restrict__ superR,
    int* __restrict__ perm, unsigned short* __restrict__ sidx,
    unsigned short* __restrict__ cellstart)
{
#pragma clang fp contract(off)
    __shared__ unsigned int hist[4096];
    __shared__ unsigned int sA[1024], sB[1024];
    __shared__ float4 cloudL[4096];
    __shared__ float4 subCR[NCHK];          // (cx,cy,cz,r) per chunk

    const int t = threadIdx.x;
    const int blk = blockIdx.x;
    const bool isB = (blk == 16);
    const int b = isB ? 0 : blk;

    #pragma unroll
    for (int i = 0; i < 4; ++i) hist[4 * t + i] = 0u;

    float X[4], Y[4], Z[4];
    unsigned int mc[4];
    if (!isB) {
        const float4* pc4 = (const float4*)(pc + (size_t)b * 12288);
        const float4 f0 = pc4[3 * t], f1 = pc4[3 * t + 1], f2 = pc4[3 * t + 2];
        X[0] = f0.x; X[1] = f0.w; X[2] = f1.z; X[3] = f2.y;
        Y[0] = f0.y; Y[1] = f1.x; Y[2] = f1.w; Y[3] = f2.z;
        Z[0] = f0.z; Z[1] = f1.y; Z[2] = f2.x; Z[3] = f2.w;
        #pragma unroll
        for (int j = 0; j < 4; ++j) mc[j] = morton16(X[j], Y[j], Z[j], 4.0f, 2.0f);
    } else {
        #pragma unroll
        for (int j = 0; j < 4; ++j) {
            const int p = 4 * t + j;
            X[j] = basis[3 * p]; Y[j] = basis[3 * p + 1]; Z[j] = basis[3 * p + 2];
            mc[j] = morton16(X[j], Y[j], Z[j], 1.0f, 8.0f);
        }
    }
    __syncthreads();
    #pragma unroll
    for (int j = 0; j < 4; ++j) atomicAdd(&hist[mc[j]], 1u);
    __syncthreads();

    // exclusive scan of hist[4096]
    const unsigned int h0 = hist[4 * t], h1 = hist[4 * t + 1],
                       h2 = hist[4 * t + 2], h3 = hist[4 * t + 3];
    sA[t] = h0 + h1 + h2 + h3;
    __syncthreads();
    unsigned int off = 1;
    #pragma unroll
    for (int s = 0; s < 10; ++s) {
        if (s & 1) sA[t] = sB[t] + ((t >= (int)off) ? sB[t - off] : 0u);
        else       sB[t] = sA[t] + ((t >= (int)off) ? sA[t - off] : 0u);
        off <<= 1;
        __syncthreads();
    }
    const unsigned int excl = (t == 0) ? 0u : sA[t - 1];
    hist[4 * t]     = excl;
    hist[4 * t + 1] = excl + h0;
    hist[4 * t + 2] = excl + h0 + h1;
    hist[4 * t + 3] = excl + h0 + h1 + h2;
    __syncthreads();

    if (!isB) {
        #pragma unroll
        for (int j = 0; j < 4; ++j) {
            const unsigned int slot = atomicAdd(&hist[mc[j]], 1u);
            const float w = (X[j] * X[j] + Y[j] * Y[j]) + Z[j] * Z[j];  // ref op order
            const float4 v = make_float4(X[j], Y[j], Z[j], w);
            cloudL[slot] = v;
            spts[((size_t)b << 12) + slot] = v;
            sidx[((size_t)b << 12) + slot] = (unsigned short)(4 * t + j);
        }
        __syncthreads();
        // cellstart[c] = first slot with cellid >= c (post-scatter hist[c] = end[c])
        #pragma unroll
        for (int i = 0; i < 4; ++i) {
            const int c = 4 * t + i;
            cellstart[((size_t)b << 12) + c] = (unsigned short)(c == 0 ? 0u : hist[c - 1]);
        }
        if (t < NCHK) {   // conservative chunk sphere
            float sx = 0.f, sy = 0.f, sz = 0.f;
            #pragma unroll
            for (int j = 0; j < CHKSZ; ++j) {
                const float4 v = cloudL[CHKSZ * t + j];
                sx += v.x; sy += v.y; sz += v.z;
            }
            const float cx = sx * 0.03125f, cy = sy * 0.03125f, cz = sz * 0.03125f;
            float m2 = 0.f;
            #pragma unroll
            for (int j = 0; j < CHKSZ; ++j) {
                const float4 v = cloudL[CHKSZ * t + j];
                const float dx = v.x - cx, dy = v.y - cy, dz = v.z - cz;
                m2 = fmaxf(m2, (dx * dx + dy * dy) + dz * dz);
            }
            const float r = sqrtf(m2) * 1.0005f + 1e-6f;
            chunkA[(b << 7) + t] = make_float4(-2.f * cx, -2.f * cy, -2.f * cz,
                                               (cx * cx + cy * cy) + cz * cz);
            chunkR[(b << 7) + t] = r;
            subCR[t] = make_float4(cx, cy, cz, r);
        }
        __syncthreads();
        if (t < 16) {     // super sphere over 8 chunk spheres (triangle ineq)
            float sx = 0.f, sy = 0.f, sz = 0.f;
            #pragma unroll
            for (int j = 0; j < 8; ++j) {
                const float4 c = subCR[8 * t + j];
                sx += c.x; sy += c.y; sz += c.z;
            }
            const float Cx = sx * 0.125f, Cy = sy * 0.125f, Cz = sz * 0.125f;
            float R = 0.f;
            #pragma unroll
            for (int j = 0; j < 8; ++j) {
                const float4 c = subCR[8 * t + j];
                const float dx = c.x - Cx, dy = c.y - Cy, dz = c.z - Cz;
                R = fmaxf(R, sqrtf((dx * dx + dy * dy) + dz * dz) + c.w);
            }
            R = R * 1.0002f + 1e-6f;
            superA[(b << 4) + t] = make_float4(-2.f * Cx, -2.f * Cy, -2.f * Cz,
                                               (Cx * Cx + Cy * Cy) + Cz * Cz);
            superR[(b << 4) + t] = R;
        }
    } else {
        #pragma unroll
        for (int j = 0; j < 4; ++j) {
            const unsigned int slot = atomicAdd(&hist[mc[j]], 1u);
            perm[slot] = 4 * t + j;
        }
    }
}

// ---------------- query kernel: quad per query, everything in LDS ----------------
__global__ __launch_bounds__(512, 4) void bps_query(
    const float* __restrict__ basis,
    const float4* __restrict__ spts,
    const float4* __restrict__ chunkA, const float* __restrict__ chunkR,
    const float4* __restrict__ superA, const float* __restrict__ superR,
    const int* __restrict__ perm, const unsigned short* __restrict__ sidx,
    const unsigned short* __restrict__ cellstart,
    float* __restrict__ out)
{
#pragma clang fp contract(off)
    __shared__ float4 cloudL[NCHK * CSTRIDE];   // 66 KB, chunk k at k*33
    __shared__ unsigned short csL[4096];        // 8 KB
    __shared__ float4 chA[NCHK];                // 2 KB
    __shared__ float  chR[NCHK];
    __shared__ float4 supA[16];
    __shared__ float  supR[16];

    const int b  = blockIdx.x >> 5;
    const int qb = blockIdx.x & 31;
    const int t  = threadIdx.x;

    // ---- stage ----
    {
        const float4* sp = spts + ((size_t)b << 12);
        #pragma unroll
        for (int i = 0; i < 8; ++i) {
            const int g = (i << 9) + t;
            cloudL[(g >> 5) * CSTRIDE + (g & 31)] = sp[g];
        }
        const unsigned int* csg = (const unsigned int*)(cellstart + ((size_t)b << 12));
        #pragma unroll
        for (int i = 0; i < 4; ++i) ((unsigned int*)csL)[(i << 9) + t] = csg[(i << 9) + t];
        if (t < NCHK) { chA[t] = chunkA[(b << 7) + t]; chR[t] = chunkR[(b << 7) + t]; }
        if (t < 16)   { supA[t] = superA[(b << 4) + t]; supR[t] = superR[(b << 4) + t]; }
    }
    __syncthreads();

    const int r    = t & 3;
    const int quad = t >> 2;                   // 0..127
    const int rank = (qb << 7) + quad;
    const int p    = perm[rank];

    const float bx = basis[3 * p], by = basis[3 * p + 1], bz = basis[3 * p + 2];
    const float bxm2 = -2.f * bx, bym2 = -2.f * by, bzm2 = -2.f * bz;
    const float bsq = (bx * bx + by * by) + bz * bz;
    const unsigned short* sig = sidx + ((size_t)b << 12);

    float bkey = __builtin_inff();
    int bslot = 0;

    auto scan8 = [&](int k) {   // quad scans chunk k, lane handles pts 4j+r
        const float4* cp = cloudL + k * CSTRIDE;
        #pragma unroll
        for (int j = 0; j < 8; ++j) {
            const int i = (j << 2) + r;
            const float4 v = cp[i];
            const float key = fmaf(v.x, bxm2, fmaf(v.y, bym2, fmaf(v.z, bzm2, v.w)));
            const int slot = (k << 5) + i;
            if (key < bkey) { bkey = key; bslot = slot; }
            else if (key == bkey) {                       // exact tie: first orig index
                if (sig[slot] < sig[bslot]) bslot = slot;
            }
        }
    };

    // ---- seed chunk from cellstart ----
    const int cell  = (int)morton16(bx, by, bz, 4.0f, 2.0f);
    int slot0 = csL[cell]; if (slot0 > 4095) slot0 = 4095;
    const int kseed = slot0 >> 5;
    scan8(kseed);

    float kmin = fminf(bkey, __shfl_xor(bkey, 1));
    kmin = fminf(kmin, __shfl_xor(kmin, 2));
    float sb = sqrtf(fmaxf(kmin + bsq, 0.f) + MARG);

    // ---- super tests: lane r tests supers 4i+r ----
    unsigned int smask = 0;
    #pragma unroll
    for (int i = 0; i < 4; ++i) {
        const int s = (i << 2) + r;
        const float4 A = supA[s];
        const float d2c = fmaf(A.x, bx, fmaf(A.y, by, fmaf(A.z, bz, A.w))) + bsq;
        const float tr = supR[s] + sb;
        if (d2c < fmaf(tr, tr, MARG)) smask |= 1u << s;
    }
    smask |= __shfl_xor(smask, 1);
    smask |= __shfl_xor(smask, 2);             // uniform within quad

    while (smask) {
        const int s = __ffs(smask) - 1; smask &= smask - 1;
        // test 8 subs of super s: lane r tests 2r, 2r+1
        unsigned int m8 = 0;
        #pragma unroll
        for (int i2 = 0; i2 < 2; ++i2) {
            const int k = (s << 3) + (r << 1) + i2;
            if (k == kseed) continue;
            const float4 A = chA[k];
            const float d2c = fmaf(A.x, bx, fmaf(A.y, by, fmaf(A.z, bz, A.w))) + bsq;
            const float tr = chR[k] + sb;
            if (d2c < fmaf(tr, tr, MARG)) m8 |= 1u << ((r << 1) + i2);
        }
        m8 |= __shfl_xor(m8, 1);
        m8 |= __shfl_xor(m8, 2);               // uniform within quad
        while (m8) {
            const int kk = __ffs(m8) - 1; m8 &= m8 - 1;
            scan8((s << 3) + kk);
            kmin = fminf(bkey, __shfl_xor(bkey, 1));
            kmin = fminf(kmin, __shfl_xor(kmin, 2));
            sb = sqrtf(fmaxf(kmin + bsq, 0.f) + MARG);   // tighten
        }
    }

    // ---- final quad reduce, lex (key, orig n) ----
    int bn = sig[bslot];
    #pragma unroll
    for (int st = 1; st <= 2; st <<= 1) {
        const float ok = __shfl_xor(bkey, st);
        const int   on = __shfl_xor(bn, st);
        const int   os = __shfl_xor(bslot, st);
        if (ok < bkey || (ok == bkey && on < bn)) { bkey = ok; bn = on; bslot = os; }
    }
    if (r == 0) {
        const float4 v = cloudL[(bslot >> 5) * CSTRIDE + (bslot & 31)];
        const float dx = v.x - bx, dy = v.y - by, dz = v.z - bz;
        const float dist = sqrtf((dx * dx + dy * dy) + dz * dz);   // ref op order
        ((float4*)out)[((size_t)b << 12) + p] = make_float4(dist, dx, dy, dz);
    }
}

extern "C" void kernel_launch(void* const* d_in, const int* in_sizes, int n_in,
                              void* d_out, int out_size, void* d_ws, size_t ws_size,
                              hipStream_t stream) {
    const float* pc    = (const float*)d_in[0];  // [16, 4096, 3]
    const float* basis = (const float*)d_in[1];  // [4096, 3]
    float* out = (float*)d_out;                  // [16, 4096, 4]

    char* ws = (char*)d_ws;
    float4*         spts   = (float4*)(ws);                        // 1 MB
    float4*         chunkA = (float4*)(ws + 1048576);              // 32 KB
    float*          chunkR = (float*) (ws + 1081344);              // 8 KB
    float4*         superA = (float4*)(ws + 1089536);              // 4 KB
    float*          superR = (float*) (ws + 1093632);              // 1 KB
    int*            perm   = (int*)   (ws + 1094656);              // 16 KB
    unsigned short* sidx   = (unsigned short*)(ws + 1111040);      // 128 KB
    unsigned short* cellst = (unsigned short*)(ws + 1242112);      // 128 KB

    bps_bin<<<dim3(17), dim3(1024), 0, stream>>>(pc, basis, spts, chunkA, chunkR,
                                                 superA, superR, perm, sidx, cellst);
    bps_query<<<dim3(512), dim3(512), 0, stream>>>(basis, spts, chunkA, chunkR,
                                                   superA, superR, perm, sidx, cellst, out);
}

// Round 10
// 35.517 us; speedup vs baseline: 10.3640x; 2.2870x over previous
//
#include <hip/hip_runtime.h>

// BPS tokenizer: per (batch, basis) argmin_n |pc[b,n]-basis[p]|^2 -> [dist,dx,dy,dz].
// B=16, N=4096, P=4096.
//
// R10: dense scalar-fma kernel stripped to the VALU floor.
//  bps_main: 512 blocks (16 b x 4 qtile x 8 nsplit) x 512 thr (8 waves, 2 blk/CU).
//   Block stages its 512-pt slice in LDS as float4 (x,y,z,|p|^2); wave w scans
//   pts [w*64,(w+1)*64) for 1024 basis (NQ=16/thread, wave-uniform ds_read_b128
//   broadcast). Hot loop per 2 pts per q: 6 v_fma + 1 v_min3 -- NO index
//   tracking (gm only). Block reduce over 8 waves (strict < keeps lowest wave id
//   = earliest n) -> partial (val, waveid) per (sp,b,p), coalesced [sp][b][p].
//  bps_merge: per query, lex-min over 8 splits (strict < keeps earliest sp),
//   rescan the winning 64-pt range from pc with the IDENTICAL fmaf chain
//   (contract off, same w op order) -> first j with key==bm = global first-index
//   tie-break (matches jnp.argmin). key = fma(x,-2bx,fma(y,-2by,fma(z,-2bz,w)))
//   = d2-|b|^2, same argmin as reference (pow2 scale exact).

#define NB 16
#define NN 4096
#define NP 4096
#define NSPLIT 8
#define NPTS 512           // pts per block
#define NW 8               // waves per block
#define THREADS 512
#define NQ 16              // basis per thread; wave covers 1024
#define QTILE 1024         // basis per block

__device__ __forceinline__ float min3f(float a, float b, float c) {
    float r;
    asm("v_min3_f32 %0, %1, %2, %3" : "=v"(r) : "v"(a), "v"(b), "v"(c));
    return r;
}

// ---------------- main: per-(qtile, nsplit) value-only argmin ----------------
__global__ __launch_bounds__(THREADS, 4) void bps_main(
    const float* __restrict__ pc,     // [B, N, 3]
    const float* __restrict__ basis,  // [P, 3]
    float2* __restrict__ vw)          // [NSPLIT][B][4096] (val, waveid)
{
#pragma clang fp contract(off)
    __shared__ float4 cloud[NPTS];        // 8 KB
    __shared__ float  red[NW][NQ][64];    // 32 KB

    const int bid = blockIdx.x;
    const int b   = bid >> 5;
    const int pt  = (bid >> 3) & 3;
    const int sp  = bid & 7;
    const int t   = threadIdx.x;
    const int l   = t & 63;
    const int w   = t >> 6;               // wave 0..7

    // ---- stage 512 pts: raw float4 into red-space, then build cloud ----
    {
        float* raw = (float*)red;         // 6 KB scratch, consumed before red use
        const float4* src4 = (const float4*)(pc + ((size_t)b * NN + (size_t)sp * NPTS) * 3);
        if (t < 384) ((float4*)raw)[t] = src4[t];
        __syncthreads();
        const float x = raw[3*t], y = raw[3*t+1], z = raw[3*t+2];
        const float wq = (x*x + y*y) + z*z;          // ref pc_sq op order
        __syncthreads();                              // raw reads done everywhere
        cloud[t] = make_float4(x, y, z, wq);
    }

    // ---- 16 basis/thread, -2 prefolded (exact): p = pt*1024 + 64q + l ----
    float bxm2[NQ], bym2[NQ], bzm2[NQ];
    {
        const int pb = (pt << 10) + l;
        #pragma unroll
        for (int q = 0; q < NQ; ++q) {
            const float* bp = basis + 3*(pb + 64*q);
            bxm2[q] = -2.f * bp[0];
            bym2[q] = -2.f * bp[1];
            bzm2[q] = -2.f * bp[2];
        }
    }
    __syncthreads();

    float gm[NQ];
    #pragma unroll
    for (int q = 0; q < NQ; ++q) gm[q] = __builtin_inff();

    const float4* cp = cloud + (w << 6);   // this wave's 64 pts
    #pragma unroll 2
    for (int i = 0; i < 32; ++i) {
        const float4 A0 = cp[2*i];         // wave-uniform -> broadcast, no conflict
        const float4 A1 = cp[2*i+1];
        #pragma unroll
        for (int q = 0; q < NQ; ++q) {
            const float d0 = fmaf(A0.x, bxm2[q], fmaf(A0.y, bym2[q], fmaf(A0.z, bzm2[q], A0.w)));
            const float d1 = fmaf(A1.x, bxm2[q], fmaf(A1.y, bym2[q], fmaf(A1.z, bzm2[q], A1.w)));
            gm[q] = min3f(gm[q], d0, d1);
        }
    }

    #pragma unroll
    for (int q = 0; q < NQ; ++q) red[w][q][l] = gm[q];
    __syncthreads();

    // ---- reduce 8 waves (strict < keeps earliest wave = earliest n), emit ----
    #pragma unroll
    for (int qq = t; qq < QTILE; qq += THREADS) {
        const int qi = qq >> 6, l2 = qq & 63;
        float bm = red[0][qi][l2];
        int   bw = 0;
        #pragma unroll
        for (int w2 = 1; w2 < NW; ++w2) {
            const float v = red[w2][qi][l2];
            if (v < bm) { bm = v; bw = w2; }
        }
        const int p = (pt << 10) + qq;
        vw[((size_t)sp << 16) + ((size_t)b << 12) + p] = make_float2(bm, __int_as_float(bw));
    }
}

// ---------------- merge: combine 8 splits, rescan 64-pt range, emit ----------------
__global__ __launch_bounds__(256) void bps_merge(
    const float* __restrict__ pc,     // [B, N, 3]
    const float* __restrict__ basis,  // [P, 3]
    const float2* __restrict__ vw,
    float* __restrict__ out)          // [B, P, 4]
{
#pragma clang fp contract(off)
    const int gid = blockIdx.x * 256 + threadIdx.x;   // 0..65535
    const int b   = gid >> 12;
    const int p   = gid & 4095;

    float bm = __builtin_inff();
    int bsp = 0, bw = 0;
    #pragma unroll
    for (int sp = 0; sp < NSPLIT; ++sp) {
        const float2 e = vw[((size_t)sp << 16) + gid];
        if (e.x < bm) { bm = e.x; bsp = sp; bw = __float_as_int(e.y); }  // strict <
    }
    const int n0 = (bsp << 9) + (bw << 6);            // winning 64-pt range

    const float bx = basis[3*p], by = basis[3*p+1], bz = basis[3*p+2];
    const float bxm2 = -2.f * bx, bym2 = -2.f * by, bzm2 = -2.f * bz;

    const float4* pc4 = (const float4*)pc + (size_t)b * 3072 + ((n0 * 3) >> 2);
    int found = 0;
    float nx = 0.f, ny = 0.f, nz = 0.f;
    for (int sub = 0; sub < 4; ++sub) {               // 4 x 16 pts
        float4 F[12];
        #pragma unroll
        for (int j = 0; j < 12; ++j) F[j] = pc4[sub * 12 + j];
        const float* Ff = (const float*)F;
        #pragma unroll
        for (int j = 0; j < 16; ++j) {                // ascending n
            const float x = Ff[3*j], y = Ff[3*j+1], z = Ff[3*j+2];
            const float wq  = (x*x + y*y) + z*z;      // identical op order
            const float key = fmaf(x, bxm2, fmaf(y, bym2, fmaf(z, bzm2, wq)));
            if (!found && key == bm) { found = 1; nx = x; ny = y; nz = z; }
        }
    }

    const float dx = nx - bx, dy = ny - by, dz = nz - bz;
    const float dist = sqrtf((dx*dx + dy*dy) + dz*dz);   // ref op order
    ((float4*)out)[((size_t)b << 12) + p] = make_float4(dist, dx, dy, dz);
}

extern "C" void kernel_launch(void* const* d_in, const int* in_sizes, int n_in,
                              void* d_out, int out_size, void* d_ws, size_t ws_size,
                              hipStream_t stream) {
    const float* pc    = (const float*)d_in[0];  // [16, 4096, 3]
    const float* basis = (const float*)d_in[1];  // [4096, 3]
    float* out = (float*)d_out;                  // [16, 4096, 4]
    float2* vw = (float2*)d_ws;                  // 4 MB partials

    bps_main<<<dim3(NB * 4 * NSPLIT), dim3(THREADS), 0, stream>>>(pc, basis, vw);
    bps_merge<<<dim3(NB * NP / 256), dim3(256), 0, stream>>>(pc, basis, vw, out);
}

// Round 11
// 29.043 us; speedup vs baseline: 12.6742x; 1.2229x over previous
//
#include <hip/hip_runtime.h>

// BPS tokenizer: per (batch, basis) argmin_n |pc[b,n]-basis[p]|^2 -> [dist,dx,dy,dz].
// B=16, N=4096, P=4096. 256 blocks x 1024 threads, one block per (b, 256-basis tile).
//
// R11 = R3 verbatim (session best, 29.0 us). Ten-round calibration: every dense
// variant converges to ~18-19 lane-FMA/cyc/SIMD (~90-100 TF, = m07 uarch ceiling);
// dense floor ~25 us, R3 runs 1.15x that. Pruned variants (R8/R9) measured 2.4-12x
// worse (divergence + occupancy). Packed-vs-scalar FLOP rates equal, so R3's
// low-instruction-count packed form with conflict-free broadcast LDS is optimal.
//
// Cloud staged in LDS as pair-SoA: pair (2j,2j+1) -> {-2x0,-2x1,-2y0,-2y1}{-2z0,-2z1,w0,w1},
// w = |p|^2. argmin key = fma(-2x,bx, fma(-2y,by, fma(-2z,bz, w))) = d2 - |b|^2 (same argmin).
// Main loop: v_pk_fma_f32 on packed pairs (2 pts/instr), v_min3 chunk-min (16-pt chunks),
// per-chunk (min, chunkId) tracking. Chunk slots rotated by chunk&7 so the final
// (post-reduction, 256-thread) rescan's divergent reads spread across banks.
// Rescan recomputes the identical fma chain -> exact equality match, first-index tie-break.

typedef __attribute__((ext_vector_type(2))) float f32x2;

#define NB 16
#define NN 4096
#define NP 4096
#define PT 256
#define NW 16              // waves per block; each scans 256 points = 16 chunks
#define THREADS 1024

__device__ __forceinline__ float min3f(float a, float b, float c) {
    float r;
    asm("v_min3_f32 %0, %1, %2, %3" : "=v"(r) : "v"(a), "v"(b), "v"(c));
    return r;
}
__device__ __forceinline__ f32x2 pk_fma(f32x2 a, f32x2 b, f32x2 c) {
    f32x2 d;
    asm("v_pk_fma_f32 %0, %1, %2, %3" : "=v"(d) : "v"(a), "v"(b), "v"(c));
    return d;
}
__device__ __forceinline__ int pslot(int p) {  // rotate pair within its 8-pair chunk
    return (p & ~7) | (((p & 7) + ((p >> 3) & 7)) & 7);
}

__global__ __launch_bounds__(THREADS, 4) void bps_kernel(
    const float* __restrict__ pc,     // [B, N, 3]
    const float* __restrict__ basis,  // [P, 3]
    float* __restrict__ out)          // [B, P, 4]
{
#pragma clang fp contract(off)
    __shared__ float4 cloudP[NN];            // 64 KB: 2048 pairs x 32B (rotated slots)
    __shared__ float  redv[NW][4][64];       // 16 KB
    __shared__ int    redi[NW][4][64];       // 16 KB

    const int b     = blockIdx.x >> 4;
    const int ptile = blockIdx.x & 15;
    const int t     = threadIdx.x;
    const int pl    = t & 63;
    const int g     = t >> 6;                // wave id 0..15

    // ---- stage 4 points -> 2 rotated pair-SoA slots ----
    {
        const float4* pc4 = (const float4*)(pc + (size_t)b * NN * 3);
        const float4 f0 = pc4[3*t+0], f1 = pc4[3*t+1], f2 = pc4[3*t+2];
        const float X[4] = {f0.x, f0.w, f1.z, f2.y};
        const float Y[4] = {f0.y, f1.x, f1.w, f2.z};
        const float Z[4] = {f0.z, f1.y, f2.x, f2.w};
        float W[4];
        #pragma unroll
        for (int j = 0; j < 4; ++j) W[j] = (X[j]*X[j] + Y[j]*Y[j]) + Z[j]*Z[j];
        #pragma unroll
        for (int pr = 0; pr < 2; ++pr) {
            const int j0 = 2*pr, j1 = 2*pr + 1;
            const int sl = pslot(2*t + pr);
            cloudP[2*sl]   = make_float4(-2.f*X[j0], -2.f*X[j1], -2.f*Y[j0], -2.f*Y[j1]);
            cloudP[2*sl+1] = make_float4(-2.f*Z[j0], -2.f*Z[j1], W[j0], W[j1]);
        }
    }

    // ---- packed basis registers for 4 basis points ----
    const int pbase = (ptile << 8) + pl;
#define DECLQ(Q) \
    const float bxs##Q = basis[3*(pbase + 64*Q) + 0]; \
    const float bys##Q = basis[3*(pbase + 64*Q) + 1]; \
    const float bzs##Q = basis[3*(pbase + 64*Q) + 2]; \
    const f32x2 bxx##Q = {bxs##Q, bxs##Q}; \
    const f32x2 byy##Q = {bys##Q, bys##Q}; \
    const f32x2 bzz##Q = {bzs##Q, bzs##Q};
    DECLQ(0) DECLQ(1) DECLQ(2) DECLQ(3)
#undef DECLQ

    __syncthreads();

    float gm0 = __builtin_inff(), gm1 = gm0, gm2 = gm0, gm3 = gm0;
    int   cb0 = 0, cb1 = 0, cb2 = 0, cb3 = 0;

    for (int c = 0; c < 16; ++c) {
        const int C = (g << 4) + c;              // global chunk id 0..255
        const float4* chunk = cloudP + (C << 4); // 16 float4 per chunk
        float cm0, cm1, cm2, cm3;
        #pragma unroll
        for (int s = 0; s < 8; ++s) {
            const float4 A1 = chunk[2*s];        // uniform addr -> broadcast
            const float4 A2 = chunk[2*s+1];
            const f32x2 xs = {A1.x, A1.y};
            const f32x2 ys = {A1.z, A1.w};
            const f32x2 zs = {A2.x, A2.y};
            const f32x2 ws = {A2.z, A2.w};
#define STEPQ(Q) { \
            const f32x2 k = pk_fma(xs, bxx##Q, pk_fma(ys, byy##Q, pk_fma(zs, bzz##Q, ws))); \
            if (s == 0) cm##Q = fminf(k.x, k.y); \
            else        cm##Q = min3f(cm##Q, k.x, k.y); }
            STEPQ(0) STEPQ(1) STEPQ(2) STEPQ(3)
#undef STEPQ
        }
        if (cm0 < gm0) { gm0 = cm0; cb0 = C; }   // strict < keeps earliest chunk
        if (cm1 < gm1) { gm1 = cm1; cb1 = C; }
        if (cm2 < gm2) { gm2 = cm2; cb2 = C; }
        if (cm3 < gm3) { gm3 = cm3; cb3 = C; }
    }

    redv[g][0][pl] = gm0; redi[g][0][pl] = cb0;
    redv[g][1][pl] = gm1; redi[g][1][pl] = cb1;
    redv[g][2][pl] = gm2; redi[g][2][pl] = cb2;
    redv[g][3][pl] = gm3; redi[g][3][pl] = cb3;

    __syncthreads();

    // ---- reduce 16 groups lexicographically, rescan winning chunk, emit ----
    if (t < PT) {
        const int pl2 = t & 63;
        const int q   = t >> 6;
        float bm = redv[0][q][pl2];
        int   bC = redi[0][q][pl2];
        #pragma unroll
        for (int gg = 1; gg < NW; ++gg) {
            const float v = redv[gg][q][pl2];
            const int   i = redi[gg][q][pl2];
            if (v < bm || (v == bm && i < bC)) { bm = v; bC = i; }
        }
        const int p  = (ptile << 8) + (q << 6) + pl2;
        const float bx = basis[3*p+0], by = basis[3*p+1], bz = basis[3*p+2];

        const float4* chunk = cloudP + (bC << 4);
        const int rot = bC & 7;
        int found = 0;
        float nx = 0.f, ny = 0.f, nz = 0.f;
        #pragma unroll
        for (int jj = 0; jj < 16; ++jj) {        // true point order for first-index
            const int s = (((jj >> 1) + rot) & 7);
            const float4 A1 = chunk[2*s];
            const float4 A2 = chunk[2*s+1];
            const int h = jj & 1;
            const float x = h ? A1.y : A1.x;
            const float y = h ? A1.w : A1.z;
            const float z = h ? A2.y : A2.x;
            const float w = h ? A2.w : A2.z;
            const float key = fmaf(x, bx, fmaf(y, by, fmaf(z, bz, w)));  // identical chain
            if (!found && key == bm) { found = 1; nx = -0.5f*x; ny = -0.5f*y; nz = -0.5f*z; }
        }
        const float dx = nx - bx, dy = ny - by, dz = nz - bz;
        const float dist = sqrtf((dx*dx + dy*dy) + dz*dz);
        ((float4*)out)[(size_t)b * NP + p] = make_float4(dist, dx, dy, dz);
    }
}

extern "C" void kernel_launch(void* const* d_in, const int* in_sizes, int n_in,
                              void* d_out, int out_size, void* d_ws, size_t ws_size,
                              hipStream_t stream) {
    const float* pc    = (const float*)d_in[0];  // [16, 4096, 3]
    const float* basis = (const float*)d_in[1];  // [4096, 3]
    float* out = (float*)d_out;                  // [16, 4096, 4]

    dim3 grid(NB * (NP / PT));  // 256 blocks
    dim3 block(THREADS);
    bps_kernel<<<grid, block, 0, stream>>>(pc, basis, out);
}